// Round 1
// baseline (148.543 us; speedup 1.0000x reference)
//
#include <hip/hip_runtime.h>

#define D 64
#define K 400
#define KT 25            // K/16 code tiles
#define BLOCK 1024
#define WPB (BLOCK / 64) // 16 waves per block

typedef _Float16 f16x8 __attribute__((ext_vector_type(8)));
typedef float f32x4 __attribute__((ext_vector_type(4)));

// scores = ||e||^2 - 2 x.e ; computed via f16 hi/lo split MFMA:
//   2e = eh + 2^-11 el,  x = xh + 2^-11 xl   (el, xl stored pre-scaled by 2^11)
//   dot(x,2e) ~= [xh.eh] + 2^-11 [xh.el + xl.eh]
// argmax over (dot - ||e||^2)  ==  argmin over score.
// ||e||^2 is folded into the hi-accumulator init (ah starts at -nrm).
__global__ __launch_bounds__(BLOCK, 4) void vq_mfma(
    const float* __restrict__ x,
    const float* __restrict__ emb,
    float* __restrict__ out,
    int nrows) {
  // B frags in MFMA lane order: [tile][frag {c0hi,c0lo,c1hi,c1lo}][lane][8]
  __shared__ __align__(16) _Float16 sB[KT][4][64][8]; // 102,400 B
  __shared__ float s_norm[K];                         // 1,600 B

  const int tid = threadIdx.x;

  // ---- stage codebook into fragment-ordered LDS ----
  for (int e = tid; e < KT * 4 * 64; e += BLOCK) {
    int t = e >> 8;
    int f = (e >> 6) & 3;
    int l = e & 63;
    int code = t * 16 + (l & 15);
    int kb = ((l >> 4) << 3) + ((f >> 1) << 5);
    const float* ep = emb + code * D + kb;
    float v[8];
    *(float4*)&v[0] = *(const float4*)ep;
    *(float4*)&v[4] = *(const float4*)(ep + 4);
    _Float16 h[8];
    if ((f & 1) == 0) {
#pragma unroll
      for (int j = 0; j < 8; ++j) h[j] = (_Float16)(2.0f * v[j]);
    } else {
#pragma unroll
      for (int j = 0; j < 8; ++j) {
        float s = 2.0f * v[j];
        _Float16 hh = (_Float16)s;
        float r = s - (float)hh;
        h[j] = (_Float16)(r * 2048.0f); // scaled 2^11: stays normal f16
      }
    }
    *(f16x8*)&sB[t][f][l][0] = *(f16x8*)&h[0];
  }
  for (int k = tid; k < K; k += BLOCK) {
    const float4* ep = (const float4*)(emb + (size_t)k * D);
    float4 s4 = {0.f, 0.f, 0.f, 0.f};
#pragma unroll
    for (int d = 0; d < 16; ++d) {
      float4 v = ep[d];
      s4.x = fmaf(v.x, v.x, s4.x);
      s4.y = fmaf(v.y, v.y, s4.y);
      s4.z = fmaf(v.z, v.z, s4.z);
      s4.w = fmaf(v.w, v.w, s4.w);
    }
    s_norm[k] = (s4.x + s4.y) + (s4.z + s4.w);
  }
  __syncthreads();

  const int lane = tid & 63;
  const int wid = tid >> 6;
  const int gw = blockIdx.x * WPB + wid;
  const int nw = gridDim.x * WPB;
  const int l15 = lane & 15;
  const int q = lane >> 4;

// 2-deep pipelined tile processing: LOADB prefetches the NEXT tile's
// B-fragments + norm while PROC consumes the current one (hides ~120cy
// LDS latency under ~150cy of MFMA+VALU per tile).
#define LOADB(Bf, Nf, T)                           \
  do {                                             \
    Bf##0 = *(const f16x8*)&sB[(T)][0][lane][0];   \
    Bf##1 = *(const f16x8*)&sB[(T)][1][lane][0];   \
    Bf##2 = *(const f16x8*)&sB[(T)][2][lane][0];   \
    Bf##3 = *(const f16x8*)&sB[(T)][3][lane][0];   \
    Nf = s_norm[(T) * 16 + l15];                   \
  } while (0)

#define PROC(Bf, Nf, T)                                                        \
  do {                                                                         \
    const float nn_ = -(Nf);                                                   \
    _Pragma("unroll") for (int a_ = 0; a_ < 2; ++a_) {                         \
      f32x4 ah = {nn_, nn_, nn_, nn_};                                         \
      f32x4 al = {0.f, 0.f, 0.f, 0.f};                                         \
      ah = __builtin_amdgcn_mfma_f32_16x16x32_f16(xh[a_][0], Bf##0, ah, 0, 0, 0); \
      ah = __builtin_amdgcn_mfma_f32_16x16x32_f16(xh[a_][1], Bf##2, ah, 0, 0, 0); \
      al = __builtin_amdgcn_mfma_f32_16x16x32_f16(xh[a_][0], Bf##1, al, 0, 0, 0); \
      al = __builtin_amdgcn_mfma_f32_16x16x32_f16(xl[a_][0], Bf##0, al, 0, 0, 0); \
      al = __builtin_amdgcn_mfma_f32_16x16x32_f16(xh[a_][1], Bf##3, al, 0, 0, 0); \
      al = __builtin_amdgcn_mfma_f32_16x16x32_f16(xl[a_][1], Bf##2, al, 0, 0, 0); \
      _Pragma("unroll") for (int i_ = 0; i_ < 4; ++i_) {                       \
        float m_ = fmaf(al[i_], 4.8828125e-4f, ah[i_]); /* ah includes -nrm */ \
        bool gt_ = m_ > bestm[a_][i_];                                         \
        bestm[a_][i_] = gt_ ? m_ : bestm[a_][i_];                              \
        bestt[a_][i_] = gt_ ? (T) : bestt[a_][i_];                             \
      }                                                                        \
    }                                                                          \
  } while (0)

  const int npair = nrows >> 5; // 32 rows per wave-iteration
  for (int p = gw; p < npair; p += nw) {
    const int row0 = p << 5;

    // ---- load + split A fragments (16 rows x 2 tiles, regs only) ----
    f16x8 xh[2][2], xl[2][2];
#pragma unroll
    for (int a = 0; a < 2; ++a)
#pragma unroll
      for (int c = 0; c < 2; ++c) {
        const float* xp =
            x + (size_t)(row0 + a * 16 + l15) * D + q * 8 + c * 32;
        float v[8];
        *(float4*)&v[0] = *(const float4*)xp;
        *(float4*)&v[4] = *(const float4*)(xp + 4);
        _Float16 hh[8], ll[8];
#pragma unroll
        for (int j = 0; j < 8; ++j) {
          _Float16 h = (_Float16)v[j];
          float r = v[j] - (float)h;
          hh[j] = h;
          ll[j] = (_Float16)(r * 2048.0f);
        }
        xh[a][c] = *(f16x8*)&hh[0];
        xl[a][c] = *(f16x8*)&ll[0];
      }

    float bestm[2][4];
    int bestt[2][4];
#pragma unroll
    for (int a = 0; a < 2; ++a)
#pragma unroll
      for (int i = 0; i < 4; ++i) {
        bestm[a][i] = -3.4e38f;
        bestt[a][i] = 0;
      }

    // ---- 25 code tiles, 2-deep software pipeline (even/odd reg sets) ----
    f16x8 bA0, bA1, bA2, bA3, bB0, bB1, bB2, bB3;
    float nA, nB;
    LOADB(bA, nA, 0);
    for (int t2 = 0; t2 < 12; ++t2) {
      LOADB(bB, nB, 2 * t2 + 1);
      PROC(bA, nA, 2 * t2);
      LOADB(bA, nA, 2 * t2 + 2);
      PROC(bB, nB, 2 * t2 + 1);
    }
    PROC(bA, nA, 24);

    // ---- argmin reduce across the 16 lanes of each row-group + write ----
#pragma unroll
    for (int a = 0; a < 2; ++a) {
      float bv[4];
      int bk[4];
#pragma unroll
      for (int i = 0; i < 4; ++i) {
        bv[i] = bestm[a][i];
        bk[i] = bestt[a][i] * 16 + l15;
      }
#pragma unroll
      for (int m = 1; m <= 8; m <<= 1) {
#pragma unroll
        for (int i = 0; i < 4; ++i) {
          float ov = __shfl_xor(bv[i], m, 64);
          int ok = __shfl_xor(bk[i], m, 64);
          bool take = (ov > bv[i]) || ((ov == bv[i]) && (ok < bk[i]));
          bv[i] = take ? ov : bv[i];
          bk[i] = take ? ok : bk[i];
        }
      }
      // row r = row0+a*16+(lane>>2); its group (lane>>4) holds that row's bk
      int j = (lane >> 2) & 3;
      int k01 = (j & 1) ? bk[1] : bk[0];
      int k23 = (j & 1) ? bk[3] : bk[2];
      int kk = (j & 2) ? k23 : k01;
      int r = row0 + a * 16 + (lane >> 2);
      // coalesced: store inst s covers full 64B segments (4 lanes x 16B)
      const f32x4* src = (const f32x4*)(emb + (size_t)kk * D);
      f32x4* dst = (f32x4*)(out + (size_t)r * D);
#pragma unroll
      for (int s = 0; s < 4; ++s) {
        int idx = (lane & 3) + (s << 2);
        f32x4 v = src[idx];
        __builtin_nontemporal_store(v, &dst[idx]);
      }
    }
  }
#undef LOADB
#undef PROC
}

extern "C" void kernel_launch(void* const* d_in, const int* in_sizes, int n_in,
                              void* d_out, int out_size, void* d_ws, size_t ws_size,
                              hipStream_t stream) {
  const float* x = (const float*)d_in[0];
  const float* emb = (const float*)d_in[1];
  float* out = (float*)d_out;
  int nrows = in_sizes[0] / D; // 262144
  vq_mfma<<<256, BLOCK, 0, stream>>>(x, emb, out, nrows);
}